// Round 1
// baseline (209.607 us; speedup 1.0000x reference)
//
#include <hip/hip_runtime.h>

#define N_ROWS 8192
#define DIM    512

typedef __attribute__((ext_vector_type(8))) short frag_ab;  // 8 bf16 (4 VGPRs)
typedef __attribute__((ext_vector_type(4))) float frag_cd;  // 4 fp32 acc

__device__ __forceinline__ unsigned short f2bf(float f) {
    unsigned u = __float_as_uint(f);
    u += 0x7FFFu + ((u >> 16) & 1u);   // RNE
    return (unsigned short)(u >> 16);
}
__device__ __forceinline__ unsigned pack2(float a, float b) {
    return (unsigned)f2bf(a) | ((unsigned)f2bf(b) << 16);
}
// order-preserving f32 -> u32 key (monotone), so atomicMax(uint) == float max
__device__ __forceinline__ unsigned enc_f32(float f) {
    unsigned u = __float_as_uint(f);
    return (u & 0x80000000u) ? ~u : (u | 0x80000000u);
}
__device__ __forceinline__ float dec_f32(unsigned k) {
    return __uint_as_float((k & 0x80000000u) ? (k & 0x7FFFFFFFu) : ~k);
}

// ---- kernel 1: fp32 -> bf16 conversion, 8 elems/thread ----
__global__ __launch_bounds__(256) void k_convert(const float* __restrict__ imgs,
                                                 const float* __restrict__ caps,
                                                 unsigned* __restrict__ bimgs,
                                                 unsigned* __restrict__ bcaps) {
    int t = blockIdx.x * 256 + threadIdx.x;          // 0 .. 1048575
    const float* src; unsigned* dst; int idx;
    if (t < (N_ROWS * DIM / 8)) { src = imgs; dst = bimgs; idx = t; }
    else { src = caps; dst = bcaps; idx = t - (N_ROWS * DIM / 8); }
    const float4* s4 = (const float4*)src + (size_t)idx * 2;
    float4 x = s4[0], y = s4[1];
    uint4 o;
    o.x = pack2(x.x, x.y); o.y = pack2(x.z, x.w);
    o.z = pack2(y.x, y.y); o.w = pack2(y.z, y.w);
    ((uint4*)dst)[idx] = o;
}

// ---- kernel 2: fp32 diag dot (1 wave/row) + init max keys ----
__global__ __launch_bounds__(256) void k_diag(const float* __restrict__ imgs,
                                              const float* __restrict__ caps,
                                              float* __restrict__ diag,
                                              unsigned* __restrict__ rowmax,
                                              unsigned* __restrict__ colmax) {
    int w = threadIdx.x >> 6, lane = threadIdx.x & 63;
    int row = blockIdx.x * 4 + w;
    const float4* ip = (const float4*)(imgs + (size_t)row * DIM);
    const float4* cp = (const float4*)(caps + (size_t)row * DIM);
    float s = 0.f;
    #pragma unroll
    for (int j = 0; j < 2; ++j) {
        float4 a = ip[lane + 64 * j], b = cp[lane + 64 * j];
        s += a.x * b.x + a.y * b.y + a.z * b.z + a.w * b.w;
    }
    #pragma unroll
    for (int m = 1; m < 64; m <<= 1) s += __shfl_xor(s, m, 64);
    if (lane == 0) { diag[row] = s; rowmax[row] = 0u; colmax[row] = 0u; }
}

// ---- kernel 3: fused bf16 NT-GEMM + diag flip + row/col max (m97 anatomy) ----
// C[i][j] = <imgs_i, caps_j>. 128x128 tile, BK=32, 4 waves of 64x64.
__global__ __launch_bounds__(256) void k_gemm(const unsigned short* __restrict__ A,
                                              const unsigned short* __restrict__ B,
                                              unsigned* __restrict__ rowmax,
                                              unsigned* __restrict__ colmax) {
    __shared__ unsigned short sA[128 * 32];   // 8 KB, row-major [row][32]
    __shared__ unsigned short sB[128 * 32];
    const int tid = threadIdx.x;
    const int w = tid >> 6, lane = tid & 63;
    const int i0 = (int)blockIdx.y << 7, j0 = (int)blockIdx.x << 7;
    const int q = lane >> 4, l15 = lane & 15;
    const int wrow = (w >> 1) << 6, wcol = (w & 1) << 6;

    frag_cd acc[4][4] = {};

    const int srow = lane >> 2;            // 0..15 (4 lanes per 32-elem row)
    const int scol = (lane & 3) << 3;      // 0,8,16,24 elems

    for (int k0 = 0; k0 < DIM; k0 += 32) {
        __syncthreads();  // prior ds_reads retired before LDS overwrite
        #pragma unroll
        for (int j = 0; j < 2; ++j) {
            int r = ((j * 4 + w) << 4) + srow;  // tile row 0..127
            const unsigned short* gA = A + (size_t)(i0 + r) * DIM + k0 + scol;
            const unsigned short* gB = B + (size_t)(j0 + r) * DIM + k0 + scol;
            // LDS dest = wave-uniform base + lane*16B (required layout)
            unsigned short* lA = sA + ((j * 4 + w) << 9) + (lane << 3);
            unsigned short* lB = sB + ((j * 4 + w) << 9) + (lane << 3);
            __builtin_amdgcn_global_load_lds(
                (const __attribute__((address_space(1))) unsigned int*)gA,
                (__attribute__((address_space(3))) unsigned int*)lA, 16, 0, 0);
            __builtin_amdgcn_global_load_lds(
                (const __attribute__((address_space(1))) unsigned int*)gB,
                (__attribute__((address_space(3))) unsigned int*)lB, 16, 0, 0);
        }
        __syncthreads();  // drains vmcnt -> LDS valid

        frag_ab af[4], bfr[4];
        #pragma unroll
        for (int r = 0; r < 4; ++r)
            af[r] = *(const frag_ab*)(sA + ((wrow + (r << 4) + l15) << 5) + (q << 3));
        #pragma unroll
        for (int c = 0; c < 4; ++c)
            bfr[c] = *(const frag_ab*)(sB + ((wcol + (c << 4) + l15) << 5) + (q << 3));
        #pragma unroll
        for (int r = 0; r < 4; ++r)
            #pragma unroll
            for (int c = 0; c < 4; ++c)
                acc[r][c] = __builtin_amdgcn_mfma_f32_16x16x32_bf16(af[r], bfr[c], acc[r][c], 0, 0, 0);
    }

    // ---- epilogue: diagonal flip + row/col max + device atomics ----
    // C/D layout: col = lane&15, row = (lane>>4)*4 + reg  [m89-verified]
    const bool dblk = (i0 == j0);
    #pragma unroll
    for (int r = 0; r < 4; ++r)
        #pragma unroll
        for (int c = 0; c < 4; ++c)
            #pragma unroll
            for (int g = 0; g < 4; ++g) {
                float f = acc[r][c][g];
                if (dblk && (wrow + (r << 4) + (q << 2) + g) == (wcol + (c << 4) + l15))
                    f = -f;   // s[i][i] = -diag
                acc[r][c][g] = f;
            }

    // row maxes: reduce over c (in-reg) then over lane&15 (xor 1,2,4,8)
    #pragma unroll
    for (int r = 0; r < 4; ++r)
        #pragma unroll
        for (int g = 0; g < 4; ++g) {
            float m = fmaxf(fmaxf(acc[r][0][g], acc[r][1][g]),
                            fmaxf(acc[r][2][g], acc[r][3][g]));
            m = fmaxf(m, __shfl_xor(m, 1, 64));
            m = fmaxf(m, __shfl_xor(m, 2, 64));
            m = fmaxf(m, __shfl_xor(m, 4, 64));
            m = fmaxf(m, __shfl_xor(m, 8, 64));
            if (l15 == 0)
                atomicMax(&rowmax[i0 + wrow + (r << 4) + (q << 2) + g], enc_f32(m));
        }
    // col maxes: reduce over r,g (in-reg) then over q (xor 16,32)
    #pragma unroll
    for (int c = 0; c < 4; ++c) {
        float m = acc[0][c][0];
        #pragma unroll
        for (int r = 0; r < 4; ++r)
            #pragma unroll
            for (int g = 0; g < 4; ++g) m = fmaxf(m, acc[r][c][g]);
        m = fmaxf(m, __shfl_xor(m, 16, 64));
        m = fmaxf(m, __shfl_xor(m, 32, 64));
        if (q == 0)
            atomicMax(&colmax[j0 + wcol + (c << 4) + l15], enc_f32(m));
    }
}

// ---- kernel 4: hinge terms + scalar reduce ----
__global__ __launch_bounds__(256) void k_final(const unsigned* __restrict__ rowmax,
                                               const unsigned* __restrict__ colmax,
                                               const float* __restrict__ diag,
                                               float* __restrict__ out) {
    int tid = threadIdx.x;
    float s = 0.f;
    for (int i = tid; i < N_ROWS; i += 256) {
        float d = diag[i];
        s += fmaxf(dec_f32(rowmax[i]) + 0.2f - d, 0.f);  // neg_img
        s += fmaxf(dec_f32(colmax[i]) + 0.2f - d, 0.f);  // neg_cap
    }
    #pragma unroll
    for (int m = 1; m < 64; m <<= 1) s += __shfl_xor(s, m, 64);
    __shared__ float red[4];
    if ((tid & 63) == 0) red[tid >> 6] = s;
    __syncthreads();
    if (tid == 0) out[0] = red[0] + red[1] + red[2] + red[3];
}

extern "C" void kernel_launch(void* const* d_in, const int* in_sizes, int n_in,
                              void* d_out, int out_size, void* d_ws, size_t ws_size,
                              hipStream_t stream) {
    const float* imgs = (const float*)d_in[0];
    const float* caps = (const float*)d_in[1];
    float* out = (float*)d_out;

    char* ws = (char*)d_ws;
    unsigned short* bimgs = (unsigned short*)ws;                       // 8 MB
    unsigned short* bcaps = (unsigned short*)(ws + 8388608);           // 8 MB
    float*    diag   = (float*)   (ws + 16777216);                     // 32 KB
    unsigned* rowmax = (unsigned*)(ws + 16777216 + 32768);             // 32 KB
    unsigned* colmax = (unsigned*)(ws + 16777216 + 65536);             // 32 KB

    k_convert<<<4096, 256, 0, stream>>>(imgs, caps, (unsigned*)bimgs, (unsigned*)bcaps);
    k_diag<<<N_ROWS / 4, 256, 0, stream>>>(imgs, caps, diag, rowmax, colmax);
    k_gemm<<<dim3(64, 64), 256, 0, stream>>>(bimgs, bcaps, rowmax, colmax);
    k_final<<<1, 256, 0, stream>>>(rowmax, colmax, diag, out);
}